// Round 16
// baseline (212.844 us; speedup 1.0000x reference)
//
#include <hip/hip_runtime.h>
#include <cstdint>
#include <cstddef>

#define NPTS 4096
#define CDIM 64
#define BDIM 8
#define KNN  20
#define ODIM 64
#define NT128 32          // 128-col tile images per batch (img layout)
#define NT64  64          // 64-col compute tiles per batch (fused)
#define LD   7            // per-lane list depth (drain-certified)

typedef unsigned long long u64;
typedef unsigned int u32;
typedef _Float16 f16;
using f16x8 = __attribute__((ext_vector_type(8))) _Float16;
using f32x4 = __attribute__((ext_vector_type(4))) float;
#define SENT   (~0ull)
#define FINF (__builtin_inff())

__device__ __forceinline__ int swz(int r) { return (r & 7) ^ ((r >> 3) & 7); }

// order-preserving float->u32 flip (ascending float == ascending u32)
__device__ __forceinline__ unsigned flip_f32(float d) {
  unsigned bits = __float_as_uint(d);
  return bits ^ (unsigned)(((int)bits >> 31) | 0x80000000u);
}

// wave64 all-reduce min (DPP), uniform via readlane 63  (R3-validated)
__device__ __forceinline__ unsigned wave_min_u32(unsigned v) {
  unsigned t;
  t = (unsigned)__builtin_amdgcn_update_dpp((int)v, (int)v, 0x111, 0xF, 0xF, false); v = t < v ? t : v;
  t = (unsigned)__builtin_amdgcn_update_dpp((int)v, (int)v, 0x112, 0xF, 0xF, false); v = t < v ? t : v;
  t = (unsigned)__builtin_amdgcn_update_dpp((int)v, (int)v, 0x114, 0xF, 0xF, false); v = t < v ? t : v;
  t = (unsigned)__builtin_amdgcn_update_dpp((int)v, (int)v, 0x118, 0xF, 0xF, false); v = t < v ? t : v;
  t = (unsigned)__builtin_amdgcn_update_dpp((int)v, (int)v, 0x142, 0xA, 0xF, false); v = t < v ? t : v;
  t = (unsigned)__builtin_amdgcn_update_dpp((int)v, (int)v, 0x143, 0xC, 0xF, false); v = t < v ? t : v;
  return (unsigned)__builtin_amdgcn_readlane((int)v, 63);
}

// 16-lane all-reduce min, float (quad xor1, xor2, row_ror4, row_ror8)
__device__ __forceinline__ float rmin16f(float v) {
  int t;
  t = __builtin_amdgcn_update_dpp(__float_as_int(v), __float_as_int(v), 0xB1,  0xF, 0xF, false);
  v = fminf(v, __int_as_float(t));
  t = __builtin_amdgcn_update_dpp(__float_as_int(v), __float_as_int(v), 0x4E,  0xF, 0xF, false);
  v = fminf(v, __int_as_float(t));
  t = __builtin_amdgcn_update_dpp(__float_as_int(v), __float_as_int(v), 0x124, 0xF, 0xF, false);
  v = fminf(v, __int_as_float(t));
  t = __builtin_amdgcn_update_dpp(__float_as_int(v), __float_as_int(v), 0x128, 0xF, 0xF, false);
  v = fminf(v, __int_as_float(t));
  return v;
}
__device__ __forceinline__ u32 rmin16u(u32 v) {
  int t;
  t = __builtin_amdgcn_update_dpp((int)v, (int)v, 0xB1,  0xF, 0xF, false); v = ((u32)t < v) ? (u32)t : v;
  t = __builtin_amdgcn_update_dpp((int)v, (int)v, 0x4E,  0xF, 0xF, false); v = ((u32)t < v) ? (u32)t : v;
  t = __builtin_amdgcn_update_dpp((int)v, (int)v, 0x124, 0xF, 0xF, false); v = ((u32)t < v) ? (u32)t : v;
  t = __builtin_amdgcn_update_dpp((int)v, (int)v, 0x128, 0xF, 0xF, false); v = ((u32)t < v) ? (u32)t : v;
  return v;
}

// med3 insertion into ascending sorted-LD (in-place descending, drops max)
__device__ __forceinline__ void insert_med3(float (&Lr)[LD], float key) {
  Lr[6] = __builtin_amdgcn_fmed3f(key, Lr[5], Lr[6]);
  Lr[5] = __builtin_amdgcn_fmed3f(key, Lr[4], Lr[5]);
  Lr[4] = __builtin_amdgcn_fmed3f(key, Lr[3], Lr[4]);
  Lr[3] = __builtin_amdgcn_fmed3f(key, Lr[2], Lr[3]);
  Lr[2] = __builtin_amdgcn_fmed3f(key, Lr[1], Lr[2]);
  Lr[1] = __builtin_amdgcn_fmed3f(key, Lr[0], Lr[1]);
  Lr[0] = fminf(key, Lr[0]);
}

// branchless insert into ascending sorted-8 of u64 keys (bubble, drops max)
__device__ __forceinline__ void ins8u(u64 (&L)[8], u64 v) {
  u64 c = v;
  #pragma unroll
  for (int j = 0; j < 8; ++j) {
    u64 lo = c < L[j] ? c : L[j];
    u64 hi = c < L[j] ? L[j] : c;
    L[j] = lo; c = hi;
  }
}

// async global->LDS, 16B per lane; LDS dest is wave-uniform base + lane*16
__device__ __forceinline__ void gl16(const char* g, char* l) {
  __builtin_amdgcn_global_load_lds(
      (const __attribute__((address_space(1))) unsigned int*)g,
      (__attribute__((address_space(3))) unsigned int*)l, 16, 0, 0);
}
// stage one 64-col tile (hi 8KB + lo 8KB) into a 16KB LDS buffer (256 thr)
__device__ __forceinline__ void stage64(const char* src_hi, char* dst, int t256) {
  const int w = t256 >> 6, lane = t256 & 63;
  const int off = w * 2048 + (lane << 4);
  gl16(src_hi + off,                 dst + w * 2048);
  gl16(src_hi + off + 1024,          dst + w * 2048 + 1024);
  gl16(src_hi + 16384 + off,         dst + 8192 + w * 2048);
  gl16(src_hi + 16384 + off + 1024,  dst + 8192 + w * 2048 + 1024);
}

// ---------------------------------------------------------------------------
// pre: ONE pass over x per 64-n segment (512 blocks, 2/CU) — UNCHANGED R13-R15
// ---------------------------------------------------------------------------
__global__ __launch_bounds__(256) void pre_kernel(const float* __restrict__ x,
                                                  const float* __restrict__ w,
                                                  float* __restrict__ sq,
                                                  float* __restrict__ sqp,
                                                  float* __restrict__ a,
                                                  float* __restrict__ cc,
                                                  char* __restrict__ img,
                                                  int* __restrict__ cnt) {
  __shared__ float xs[CDIM][64];     // 16KB [c][n']
  __shared__ float wa[CDIM][ODIM];   // 16KB
  __shared__ float wc[CDIM][ODIM];   // 16KB
  __shared__ char  limg[16384];      // 16KB (hi 8K + lo 8K for these 64 n)

  const int tid = threadIdx.x;
  const int blk = blockIdx.x;
  const int b = blk >> 6, seg = blk & 63;
  const int n0 = seg * 64;
  if (blk == 0 && tid == 0) *cnt = 0;

  const float* xb = x + (size_t)b * CDIM * NPTS;
  #pragma unroll
  for (int p = 0; p < 16; ++p) {
    int idx = p * 256 + tid;                 // 0..4095
    int c = idx >> 6, n = idx & 63;
    xs[c][n] = xb[(size_t)c * NPTS + n0 + n];
  }
  #pragma unroll
  for (int p = 0; p < 16; ++p) {
    int idx = p * 256 + tid;
    int o = idx & 63, c = idx >> 6;
    float w1 = w[o * 128 + c], w2 = w[o * 128 + 64 + c];
    wa[c][o] = w1 - w2;
    wc[c][o] = w2;
  }
  __syncthreads();

  // sq: ascending c per n, single thread per n (bit-identical)
  if (tid < 64) {
    float s = 0.f;
    #pragma unroll
    for (int c = 0; c < CDIM; ++c) { float v = xs[c][tid]; s += v * v; }
    int n = n0 + tid;
    sq[b * NPTS + n] = s;
    int t = n >> 6, j0 = n & 63;
    sqp[(((size_t)b * NT64 + t) * 16 + (j0 & 15)) * 4 + (j0 >> 4)] = s;
  }

  // proj: identical per-o accumulation order as R12-R15
  {
    const int og = tid >> 6, nl = tid & 63;
    float aa[16], ac[16];
    #pragma unroll
    for (int qq = 0; qq < 16; ++qq) { aa[qq] = ac[qq] = 0.f; }
    #pragma unroll 4
    for (int c = 0; c < CDIM; ++c) {
      float xv = xs[c][nl];
      #pragma unroll
      for (int q4 = 0; q4 < 4; ++q4) {
        float4 va = *(const float4*)&wa[c][og * 16 + q4 * 4];
        float4 vc = *(const float4*)&wc[c][og * 16 + q4 * 4];
        aa[q4*4+0] += va.x * xv; aa[q4*4+1] += va.y * xv;
        aa[q4*4+2] += va.z * xv; aa[q4*4+3] += va.w * xv;
        ac[q4*4+0] += vc.x * xv; ac[q4*4+1] += vc.y * xv;
        ac[q4*4+2] += vc.z * xv; ac[q4*4+3] += vc.w * xv;
      }
    }
    size_t ga = (size_t)(b * NPTS + n0 + nl) * ODIM + og * 16;
    #pragma unroll
    for (int q4 = 0; q4 < 4; ++q4) {
      *(float4*)&a [ga + q4 * 4] = *(float4*)&aa[q4 * 4];
      *(float4*)&cc[ga + q4 * 4] = *(float4*)&ac[q4 * 4];
    }
  }

  // img: identical bytes/layout to R12-R15
  {
    const int npl = tid & 63;
    const int half = tid >> 6;                // c-base half*16
    const int np128 = (seg & 1) * 64 + npl;
    const int sw = swz(np128) << 4;
    #pragma unroll
    for (int oct = 0; oct < 2; ++oct) {
      const int cb = half * 16 + oct * 8;
      f16x8 hv, lv;
      #pragma unroll
      for (int j = 0; j < 8; ++j) {
        float v = xs[cb + j][npl];
        f16 h = (f16)v;
        hv[j] = h;
        lv[j] = (f16)(v - (float)h);
      }
      int byt = (npl * 128 + cb * 2) ^ sw;    // within this 8KB half
      *(f16x8*)(limg + byt) = hv;
      *(f16x8*)(limg + 8192 + byt) = lv;
    }
  }
  __syncthreads();
  {
    char* dstbase = img + ((size_t)b * NT128 + (seg >> 1)) * 32768
                        + (size_t)(seg & 1) * 8192;
    #pragma unroll
    for (int i = 0; i < 2; ++i) {
      *(float4*)(dstbase + i * 4096 + tid * 16) =
          *(const float4*)(limg + i * 4096 + tid * 16);
      *(float4*)(dstbase + 16384 + i * 4096 + tid * 16) =
          *(const float4*)(limg + 8192 + i * 4096 + tid * 16);
    }
  }
}

// ---------------------------------------------------------------------------
// Fused dist+top20+OUT. R15's structure with the A-fragment offset BUG FIXED:
// the XOR swizzle must wrap the FULL element offset including the ks*64-byte
// term — (base+64)^swn, NOT (base^swn)+64 (they differ when swz(nn)>=4).
// byt0/byt1 are both precomputed with the XOR applied last (matches R13/R14
// and the B-side reads). Depth-7 lists; drain certificate covers truncation.
// ---------------------------------------------------------------------------
__global__ __launch_bounds__(512, 2) void fused_knn(const char* __restrict__ img,
                                                    const float* __restrict__ sq,
                                                    const float* __restrict__ sqp,
                                                    int* __restrict__ knn,
                                                    int* __restrict__ list,
                                                    int* __restrict__ cnt,
                                                    const float* __restrict__ pa,
                                                    const float* __restrict__ pcc,
                                                    const float* __restrict__ gamma,
                                                    const float* __restrict__ beta,
                                                    const float* __restrict__ mean,
                                                    const float* __restrict__ var,
                                                    float* __restrict__ pout) {
  __shared__ char XB[2][2][16384];     // [grp][dbuf] — 64 KB

  const int tid  = threadIdx.x;
  const int grp  = tid >> 8;           // 0: tiles 0-31, 1: tiles 32-63
  const int t256 = tid & 255;
  const int lane = tid & 63;
  const int w4   = t256 >> 6;          // wave within group (0..3)
  const int q = lane >> 4;
  const int s = lane & 15;

  const int blk = blockIdx.x;
  const int b  = blk >> 6;
  const int r0 = (blk & 63) * 64;
  const char* imgb = img + (size_t)b * (NT128 * 32768);
  const float* sqb = sq + (size_t)b * NPTS;
  const float4* sqp4 = (const float4*)(sqp + (size_t)b * NT64 * 64);

  const int tb = grp * 32;             // group tile base
  #define TSRC(tile) (imgb + (size_t)((tile) >> 1) * 32768 + (size_t)((tile) & 1) * 8192)

  stage64(TSRC(tb), XB[grp][0], t256);   // group's tile 0

  // A-fragment base + swizzled offsets (XOR applied LAST — the R15 fix)
  const char* atp;
  int byt0, byt1;
  {
    const int grow = r0 + w4 * 16 + s;
    atp = imgb + (size_t)(grow >> 7) * 32768;
    const int nn = grow & 127;
    const int swn = swz(nn) << 4;
    byt0 = (nn * 128 + q * 16) ^ swn;        // ks=0
    byt1 = (nn * 128 + 64 + q * 16) ^ swn;   // ks=1
  }

  float sqr[4];
  #pragma unroll
  for (int reg = 0; reg < 4; ++reg) sqr[reg] = sqb[r0 + w4 * 16 + q * 4 + reg];

  float L[4][LD];
  #pragma unroll
  for (int reg = 0; reg < 4; ++reg)
    #pragma unroll
    for (int j = 0; j < LD; ++j) L[reg][j] = FINF;

  __syncthreads();                 // tile-0 staging drained (both groups)

  for (int t = 0; t < 32; ++t) {
    if (t + 1 < 32)
      stage64(TSRC(tb + t + 1), XB[grp][(t + 1) & 1], t256);

    // reload A fragments (laundered base -> loads stay in-loop, L2 hits)
    const char* la = atp;
    asm volatile("" : "+v"(la));
    f16x8 Ah0 = *(const f16x8*)(la + byt0);
    f16x8 Ah1 = *(const f16x8*)(la + byt1);
    f16x8 Al0 = *(const f16x8*)(la + 16384 + byt0);
    f16x8 Al1 = *(const f16x8*)(la + 16384 + byt1);

    const char* XBc = XB[grp][t & 1];
    const int tile = tb + t;
    const float4 sm4 = sqp4[tile * 16 + s];   // sq[tile*64 + e*16 + s]
    #pragma unroll
    for (int e = 0; e < 4; ++e) {
      const int j = e * 16 + s;
      const int swj = swz(j) << 4;
      f32x4 acc = {0.f, 0.f, 0.f, 0.f};
      {
        int byt = (j * 128 + q * 16) ^ swj;          // ks=0
        f16x8 Bh = *(const f16x8*)(XBc + byt);
        f16x8 Bl = *(const f16x8*)(XBc + 8192 + byt);
        acc = __builtin_amdgcn_mfma_f32_16x16x32_f16(Ah0, Bh, acc, 0, 0, 0);
        acc = __builtin_amdgcn_mfma_f32_16x16x32_f16(Ah0, Bl, acc, 0, 0, 0);
        acc = __builtin_amdgcn_mfma_f32_16x16x32_f16(Al0, Bh, acc, 0, 0, 0);
      }
      {
        int byt = (j * 128 + 64 + q * 16) ^ swj;     // ks=1
        f16x8 Bh = *(const f16x8*)(XBc + byt);
        f16x8 Bl = *(const f16x8*)(XBc + 8192 + byt);
        acc = __builtin_amdgcn_mfma_f32_16x16x32_f16(Ah1, Bh, acc, 0, 0, 0);
        acc = __builtin_amdgcn_mfma_f32_16x16x32_f16(Ah1, Bl, acc, 0, 0, 0);
        acc = __builtin_amdgcn_mfma_f32_16x16x32_f16(Al1, Bh, acc, 0, 0, 0);
      }
      const float sm = (&sm4.x)[e];
      const u32 klo = (u32)(tile * 4 + e);    // = mcol >> 4
      #pragma unroll
      for (int reg = 0; reg < 4; ++reg) {
        float v = (sqr[reg] + sm) - 2.0f * acc[reg];   // same expr as R4-R14
        float key = __uint_as_float((__float_as_uint(v) & 0xFFFFFF00u) | klo);
        insert_med3(L[reg], key);
      }
    }
    __syncthreads();
  }

  // merge: group-1 dumps lists; group-0 merges (exact union top-LD)
  float* mbuf = (float*)XB;              // [0, 28672)
  int*   kbuf = (int*)((char*)XB + 32768);          // 64 x 20 ints
  float* tile = (float*)((char*)XB + 40960);        // 64 x 65 floats
  if (grp == 1) {
    #pragma unroll
    for (int reg = 0; reg < 4; ++reg)
      #pragma unroll
      for (int j = 0; j < LD; ++j)
        mbuf[((reg * LD + j) * 4 + w4) * 64 + lane] = L[reg][j];
  }
  __syncthreads();

  if (grp == 0) {
    #pragma unroll
    for (int reg = 0; reg < 4; ++reg)
      #pragma unroll
      for (int j = 0; j < LD; ++j)
        insert_med3(L[reg], mbuf[((reg * LD + j) * 4 + w4) * 64 + lane]);

    // pops: 21 rounds per row; certificates identical (depth re-indexed)
    #pragma unroll
    for (int reg = 0; reg < 4; ++reg) {
      bool flg = false;
      int iA = 0, iB = 0;
      u32 k20 = 0, k21 = 0;
      for (int r = 0; r < KNN + 1; ++r) {
        float head = L[reg][0];
        float wkey = rmin16f(head);
        unsigned long long bal = __ballot(head == wkey);
        unsigned qm = (unsigned)((bal >> (q * 16)) & 0xFFFFull);
        int swin = __ffs((int)qm) - 1;
        flg = flg || ((qm & (qm - 1u)) != 0u);
        u32 kb = __float_as_uint(wkey);
        int idx = (int)(((kb & 0xFFu) << 4) | (u32)swin);
        if (r < 16) { if (s == r) iA = idx; }
        else if (r < KNN) { if (s == r - 16) iB = idx; }
        if (r == KNN - 1) k20 = kb;
        if (r == KNN)     k21 = kb;
        bool own = (head == wkey) && (s == swin);
        #pragma unroll
        for (int jj = 0; jj < LD - 1; ++jj) L[reg][jj] = own ? L[reg][jj + 1] : L[reg][jj];
        L[reg][LD - 1] = own ? FINF : L[reg][LD - 1];
      }
      flg = flg || ((k20 >> 8) == (k21 >> 8));
      u32 alive = (__float_as_uint(L[reg][0]) == __float_as_uint(FINF)) ? 0u : 1u;
      flg = flg || (rmin16u(alive) == 0u);
      const int lrow = w4 * 16 + q * 4 + reg;
      size_t grow = (size_t)b * NPTS + r0 + lrow;
      knn[grow * KNN + s] = iA;
      kbuf[lrow * KNN + s] = iA;
      if (s < 4) { knn[grow * KNN + 16 + s] = iB; kbuf[lrow * KNN + 16 + s] = iB; }
      if (s == 0 && flg) { int p = atomicAdd(cnt, 1); list[p] = (int)grow; }
    }
  }
  __syncthreads();

  // inline out: all 8 waves, 8 rows each
  {
    const int wv8 = tid >> 6;
    float inv  = gamma[lane] / sqrtf(var[lane] + 1e-5f);
    float bias = beta[lane] - mean[lane] * inv;
    for (int rr = 0; rr < 8; ++rr) {
      int row = wv8 * 8 + rr;
      size_t base = (size_t)b * NPTS + r0 + row;
      float av = pa[base * ODIM + lane];
      const int* kr = kbuf + row * KNN;
      float m = -INFINITY;
      #pragma unroll
      for (int k = 0; k < KNN; ++k) {
        int jj = kr[k];
        m = fmaxf(m, av + pcc[((size_t)b * NPTS + jj) * ODIM + lane]);
      }
      float v = m * inv + bias;
      tile[row * 65 + lane] = v > 0.f ? v : 0.f;
    }
  }
  __syncthreads();
  #pragma unroll
  for (int t8 = 0; t8 < 8; ++t8) {
    int o = (tid >> 6) * 8 + t8;
    pout[((size_t)b * ODIM + o) * NPTS + r0 + lane] = tile[lane * 65 + o];
  }
  #undef TSRC
}

// ---------------------------------------------------------------------------
// Exact fp32 brute-force for flagged rows (R7-R14-validated) + out fixup.
// ---------------------------------------------------------------------------
__global__ __launch_bounds__(256) void fallback_knn(const float* __restrict__ x,
                                                    const float* __restrict__ sq,
                                                    const int* __restrict__ cnt,
                                                    const int* __restrict__ list,
                                                    int* __restrict__ knn,
                                                    const float* __restrict__ pa,
                                                    const float* __restrict__ pcc,
                                                    const float* __restrict__ gamma,
                                                    const float* __restrict__ beta,
                                                    const float* __restrict__ mean,
                                                    const float* __restrict__ var,
                                                    float* __restrict__ pout) {
  __shared__ float xrl[CDIM];
  __shared__ u64 cand[4 * KNN];
  __shared__ int kfix[KNN];
  const int tid = threadIdx.x, lane = tid & 63, wv = tid >> 6;
  const int count = *cnt;

  for (int it = blockIdx.x; it < count; it += gridDim.x) {
    const int g = list[it];
    const int b = g >> 12, r = g & (NPTS - 1);
    const float* xb  = x  + (size_t)b * CDIM * NPTS;
    const float* sqb = sq + (size_t)b * NPTS;
    if (tid < CDIM) xrl[tid] = xb[(size_t)tid * NPTS + r];
    __syncthreads();
    const float sqr = sqb[r];

    u64 L[8];
    #pragma unroll
    for (int j = 0; j < 8; ++j) L[j] = SENT;
    #pragma unroll
    for (int ii = 0; ii < 4; ++ii) {
      const int i = wv * 4 + ii;
      float a0 = 0.f, a1 = 0.f, a2 = 0.f, a3 = 0.f;
      const float* xp = xb + i * 256 + lane * 4;
      #pragma unroll
      for (int c4 = 0; c4 < 16; ++c4) {
        float4 xr4 = *(const float4*)&xrl[c4 * 4];
        #pragma unroll
        for (int j = 0; j < 4; ++j) {
          float4 xv = *(const float4*)(xp + (size_t)(c4 * 4 + j) * NPTS);
          float xr = (&xr4.x)[j];
          a0 += xr * xv.x; a1 += xr * xv.y; a2 += xr * xv.z; a3 += xr * xv.w;
        }
      }
      int mb = i * 256 + lane * 4;
      float4 sv = *(const float4*)(sqb + mb);
      ins8u(L, ((u64)flip_f32(sqr + sv.x - 2.0f * a0) << 12) | (unsigned)mb);
      ins8u(L, ((u64)flip_f32(sqr + sv.y - 2.0f * a1) << 12) | (unsigned)(mb + 1));
      ins8u(L, ((u64)flip_f32(sqr + sv.z - 2.0f * a2) << 12) | (unsigned)(mb + 2));
      ins8u(L, ((u64)flip_f32(sqr + sv.w - 2.0f * a3) << 12) | (unsigned)(mb + 3));
    }

    u64 last = 0; bool done = false;
    for (int rr = 0; rr < KNN; ++rr) {
      bool need = (L[0] == SENT) && !done;
      if (__any(need)) {
        if (need) {
          #pragma unroll
          for (int j = 0; j < 8; ++j) L[j] = SENT;
          for (int ii = 0; ii < 4; ++ii) {
            const int i = wv * 4 + ii;
            float a0 = 0.f, a1 = 0.f, a2 = 0.f, a3 = 0.f;
            const float* xp = xb + i * 256 + lane * 4;
            #pragma unroll
            for (int c4 = 0; c4 < 16; ++c4) {
              float4 xr4 = *(const float4*)&xrl[c4 * 4];
              #pragma unroll
              for (int j = 0; j < 4; ++j) {
                float4 xv = *(const float4*)(xp + (size_t)(c4 * 4 + j) * NPTS);
                float xr = (&xr4.x)[j];
                a0 += xr * xv.x; a1 += xr * xv.y; a2 += xr * xv.z; a3 += xr * xv.w;
              }
            }
            int mb = i * 256 + lane * 4;
            float4 sv = *(const float4*)(sqb + mb);
            u64 v;
            v = ((u64)flip_f32(sqr + sv.x - 2.0f * a0) << 12) | (unsigned)mb;       ins8u(L, v > last ? v : SENT);
            v = ((u64)flip_f32(sqr + sv.y - 2.0f * a1) << 12) | (unsigned)(mb + 1); ins8u(L, v > last ? v : SENT);
            v = ((u64)flip_f32(sqr + sv.z - 2.0f * a2) << 12) | (unsigned)(mb + 2); ins8u(L, v > last ? v : SENT);
            v = ((u64)flip_f32(sqr + sv.w - 2.0f * a3) << 12) | (unsigned)(mb + 3); ins8u(L, v > last ? v : SENT);
          }
          if (L[0] == SENT) done = true;
        }
      }
      unsigned keyH = (unsigned)(L[0] >> 12);
      unsigned wkey = wave_min_u32(keyH);
      unsigned mc   = (keyH == wkey) ? (unsigned)(L[0] & 0xFFF) : 0xFFFFFFFFu;
      unsigned wm   = wave_min_u32(mc);
      u64 wsel = ((u64)wkey << 12) | wm;
      if (lane == rr) cand[wv * KNN + rr] = wsel;
      bool win = (L[0] == wsel);
      #pragma unroll
      for (int j = 0; j < 7; ++j) L[j] = win ? L[j + 1] : L[j];
      L[7] = win ? SENT : L[7];
      last = wsel;
    }
    __syncthreads();

    if (wv == 0) {                       // merge 80 candidates -> top 20
      u64 c0 = cand[lane < 4 * KNN ? lane : 0];
      if (lane >= 4 * KNN) c0 = SENT;
      u64 c1 = (lane < 4 * KNN - 64) ? cand[64 + lane] : SENT;
      int myidx = 0;
      for (int rr = 0; rr < KNN; ++rr) {
        u64 mn = c0 < c1 ? c0 : c1;
        unsigned keyH = (unsigned)(mn >> 12);
        unsigned wkey = wave_min_u32(keyH);
        unsigned mc   = (keyH == wkey) ? (unsigned)(mn & 0xFFF) : 0xFFFFFFFFu;
        unsigned wm   = wave_min_u32(mc);
        u64 wsel = ((u64)wkey << 12) | wm;
        if (lane == rr) myidx = (int)wm;
        if (c0 == wsel)      { c0 = c1; c1 = SENT; }
        else if (c1 == wsel) { c1 = SENT; }
      }
      if (lane < KNN) {
        knn[(size_t)g * KNN + lane] = myidx;
        kfix[lane] = myidx;
      }
    }
    __syncthreads();

    if (wv == 0) {                       // out fixup for this row (lane = o)
      float inv  = gamma[lane] / sqrtf(var[lane] + 1e-5f);
      float bias = beta[lane] - mean[lane] * inv;
      float av = pa[(size_t)g * ODIM + lane];
      float m = -INFINITY;
      #pragma unroll
      for (int k = 0; k < KNN; ++k) {
        int jj = kfix[k];
        m = fmaxf(m, av + pcc[((size_t)b * NPTS + jj) * ODIM + lane]);
      }
      float v = m * inv + bias;
      pout[((size_t)b * ODIM + lane) * NPTS + r] = v > 0.f ? v : 0.f;
    }
    __syncthreads();
  }
}

// ---------------------------------------------------------------------------
extern "C" void kernel_launch(void* const* d_in, const int* in_sizes, int n_in,
                              void* d_out, int out_size, void* d_ws, size_t ws_size,
                              hipStream_t stream) {
  const float* x     = (const float*)d_in[0];
  const float* w     = (const float*)d_in[1];
  const float* gamma = (const float*)d_in[2];
  const float* beta  = (const float*)d_in[3];
  const float* mean  = (const float*)d_in[4];
  const float* var   = (const float*)d_in[5];
  float* out = (float*)d_out;

  char* wsb = (char*)d_ws;
  size_t off = 0;
  int*   knn   = (int*)(wsb + off);   off += (size_t)BDIM * NPTS * KNN * 4;   // 2.62 MB
  int*   list  = (int*)(wsb + off);   off += (size_t)BDIM * NPTS * 4;         // 0.13 MB
  int*   cnt   = (int*)(wsb + off);   off += 256;
  float* sqw   = (float*)(wsb + off); off += (size_t)BDIM * NPTS * 4;         // 0.13 MB
  float* sqp   = (float*)(wsb + off); off += (size_t)BDIM * NPTS * 4;         // 0.13 MB
  float* a     = (float*)(wsb + off); off += (size_t)BDIM * NPTS * ODIM * 4;  // 8 MB
  float* cc    = (float*)(wsb + off); off += (size_t)BDIM * NPTS * ODIM * 4;  // 8 MB
  char*  img   = wsb + off;           off += (size_t)BDIM * NT128 * 32768;    // 8 MB
  (void)ws_size;

  pre_kernel  <<<BDIM * NPTS / 64, 256, 0, stream>>>(x, w, sqw, sqp, a, cc, img, cnt);
  fused_knn   <<<512, 512, 0, stream>>>(img, sqw, sqp, knn, list, cnt,
                                        a, cc, gamma, beta, mean, var, out);
  fallback_knn<<<2048, 256, 0, stream>>>(x, sqw, cnt, list, knn,
                                         a, cc, gamma, beta, mean, var, out);
}